// Round 14
// baseline (55.723 us; speedup 1.0000x reference)
//
#include <hip/hip_runtime.h>
#include <hip/hip_bf16.h>
#include <math.h>

#define NDIM 4096
#define MDIM 4096
#define LDIM 512
#define KDIM 1024

typedef float f32x4 __attribute__((ext_vector_type(4)));

// Transposed-blocked fp8 operands: [k>>3][point][k&7] -> u64 per (octet,point)
__device__ __align__(16) unsigned long long g_At[(size_t)128 * NDIM];
__device__ __align__(16) unsigned long long g_Bt[(size_t)128 * MDIM];

#define GLOBAL_AS __attribute__((address_space(1)))
#define LDS_AS __attribute__((address_space(3)))

__device__ __forceinline__ void gload_lds16(void* lds, const void* g) {
  __builtin_amdgcn_global_load_lds((const GLOBAL_AS void*)g, (LDS_AS void*)lds, 16, 0, 0);
}

// ---------------------------------------------------------------------------
// scale_kernel: ws[0] = |var| / sum_l exp(-0.5*lam_l)
// ---------------------------------------------------------------------------
__global__ __launch_bounds__(512) void scale_kernel(const float* __restrict__ lam,
                                                    const float* __restrict__ var,
                                                    float* __restrict__ ws) {
  int l = threadIdx.x;
  float v = expf(-0.5f * lam[l]);
  #pragma unroll
  for (int off = 32; off > 0; off >>= 1) v += __shfl_down(v, off, 64);
  __shared__ float red[8];
  if ((l & 63) == 0) red[l >> 6] = v;
  __syncthreads();
  if (l == 0) {
    float t = 0.f;
    #pragma unroll
    for (int i = 0; i < 8; ++i) t += red[i];
    ws[0] = fabsf(var[0]) / t;
  }
}

// ---------------------------------------------------------------------------
// Phase kernel (R13 verbatim): thread -> (point p, octet o); 8 l's each;
// cos-octet -> k-octet o, sin-octet -> k-octet o+64, fp8 e4m3 packed 8B.
// A rows weighted by w_l; B cols unweighted. Coalesced 512B/wave stores.
// ---------------------------------------------------------------------------
__global__ __launch_bounds__(256) void phase_kernel(const float* __restrict__ x,
                                                    const float* __restrict__ y,
                                                    const float* __restrict__ freqs,
                                                    const float* __restrict__ lam) {
  int tid = threadIdx.x;
  int blk = blockIdx.x;
  int p = (blk & 127) * 64 + (tid & 63);
  int o = (blk >> 7) * 4 + (tid >> 6);
  bool isA = (p < NDIM);
  int rr = isA ? p : (p - NDIM);
  const float* pt = (isA ? x : y) + 3 * (size_t)rr;
  float p0 = pt[0], p1 = pt[1], p2 = pt[2];

  float cv[8], sv[8];
  #pragma unroll
  for (int i = 0; i < 8; ++i) {
    int li = o * 8 + i;
    float px = p0 * freqs[3 * li] + p1 * freqs[3 * li + 1] + p2 * freqs[3 * li + 2];
    float sn, cs;
    __sincosf(px, &sn, &cs);
    float wl = isA ? expf(-0.5f * lam[li]) : 1.0f;
    cv[i] = cs * wl;
    sv[i] = sn * wl;
  }
  union { int i2[2]; unsigned long long u; } pc, ps;
  pc.i2[0] = __builtin_amdgcn_cvt_pk_fp8_f32(cv[0], cv[1], 0, 0);
  pc.i2[0] = __builtin_amdgcn_cvt_pk_fp8_f32(cv[2], cv[3], pc.i2[0], 1);
  pc.i2[1] = __builtin_amdgcn_cvt_pk_fp8_f32(cv[4], cv[5], 0, 0);
  pc.i2[1] = __builtin_amdgcn_cvt_pk_fp8_f32(cv[6], cv[7], pc.i2[1], 1);
  ps.i2[0] = __builtin_amdgcn_cvt_pk_fp8_f32(sv[0], sv[1], 0, 0);
  ps.i2[0] = __builtin_amdgcn_cvt_pk_fp8_f32(sv[2], sv[3], ps.i2[0], 1);
  ps.i2[1] = __builtin_amdgcn_cvt_pk_fp8_f32(sv[4], sv[5], 0, 0);
  ps.i2[1] = __builtin_amdgcn_cvt_pk_fp8_f32(sv[6], sv[7], ps.i2[1], 1);

  unsigned long long* base = (isA ? g_At : g_Bt) + rr;
  base[(size_t)o * NDIM]        = pc.u;   // k-octet o       (cos)
  base[(size_t)(o + 64) * NDIM] = ps.u;   // k-octet o + 64  (sin)
}

// ---------------------------------------------------------------------------
// GEMM: C = s*(A @ B^T), fp8 e4m3, K=1024. 256x256 tile, BK=64, 8 waves 2Mx4N.
// A staged in LDS (32 KiB: [2 buf][2 kk][oct][256 r][8B], row-XOR r^(oct<<2)
// -> conflict-free b64 reads, 16B-contiguous gload sources). B direct
// global->reg coalesced (R13). R12 pipeline: AREAD 1 phase ahead w/ LGKM(8),
// B prefetch 1 phase ahead (compiler-tracked), STAGE 2 phases ahead with
// manual VMCNT(5) (FIFO-derived; never 0 mid-loop), 1 barrier/phase.
// ---------------------------------------------------------------------------
__global__ __launch_bounds__(512, 2) void gemm_kernel(float* __restrict__ C,
                                                      const float* __restrict__ ws) {
  __shared__ __align__(16) unsigned long long Asl[2][2][1024];   // 4 x 8 KiB

  int bid = blockIdx.x;                   // 0..255
  int xcd = bid & 7;                      // supertile map (R10/R12, verified)
  int slt = bid >> 3;
  int sup = 2 * xcd + (slt >> 4);
  int w_  = slt & 15;
  int brow = ((sup >> 2) * 4 + (w_ >> 2)) * 256;
  int bcol = ((sup & 3) * 4 + (w_ & 3)) * 256;

  int tid  = threadIdx.x;
  int lane = tid & 63;
  int wid  = tid >> 6;                    // 0..7
  int wm   = wid >> 2;                    // 0..1
  int wn   = wid & 3;                     // 0..3
  int fr   = lane & 15;
  int oct  = lane >> 4;                   // 0..3

  float s_val = ws[0];

  // A ds_read base: byte = oct*2048 + (fr ^ (oct<<2))*8 ; + wm*1024 + m*128
  int aoff = oct * 2048 + ((fr ^ (oct << 2)) << 3) + wm * 1024;

  // A staging source constants: thread -> (o = tid>>7, row-pair i = tid&127)
  int so  = tid >> 7;
  int si  = tid & 127;
  const unsigned long long* gAsrc =
      g_At + (size_t)so * NDIM + brow + ((2 * si) ^ (so << 2));

  // B fragment base (R13): octet lane>>4, col = bcol + wn*64 + fr
  const unsigned long long* Bt = g_Bt + (size_t)oct * MDIM + (bcol + wn * 64 + fr);

  f32x4 acc[8][4] = {};
  long s0_0, s0_1, s0_2, s0_3, s0_4, s0_5, s0_6, s0_7;   // A set 0 (LDS)
  long s1_0, s1_1, s1_2, s1_3, s1_4, s1_5, s1_6, s1_7;   // A set 1 (LDS)
  long u0, u1, u2, u3;                                   // B set U (direct)
  long v0, v1, v2, v3;                                   // B set V (direct)

  // Stage A half-tile (T,KK): 1 gload16/thread (8 KiB slab).
#define STAGE(T1, KK)                                                        \
  {                                                                          \
    char* d_ = (char*)&Asl[(T1) & 1][(KK)][0] + tid * 16;                    \
    const unsigned long long* s_ = gAsrc + (size_t)((T1) * 8 + (KK) * 4) * NDIM; \
    gload_lds16(d_, s_);                                                     \
  }

#define VMCNT(N) asm volatile("s_waitcnt vmcnt(" #N ")" ::: "memory")
#define LGKM(N)  asm volatile("s_waitcnt lgkmcnt(" #N ")" ::: "memory")
#define SCHED0   __builtin_amdgcn_sched_barrier(0)
#define BAR      __builtin_amdgcn_s_barrier()

#define AREAD(S, T, KK)                                                      \
  { const char* Ab_ = (const char*)&Asl[(T) & 1][(KK)][0] + aoff;            \
    S##0 = *(const long*)(Ab_ + 0 * 128);                                    \
    S##1 = *(const long*)(Ab_ + 1 * 128);                                    \
    S##2 = *(const long*)(Ab_ + 2 * 128);                                    \
    S##3 = *(const long*)(Ab_ + 3 * 128);                                    \
    S##4 = *(const long*)(Ab_ + 4 * 128);                                    \
    S##5 = *(const long*)(Ab_ + 5 * 128);                                    \
    S##6 = *(const long*)(Ab_ + 6 * 128);                                    \
    S##7 = *(const long*)(Ab_ + 7 * 128); }

#define BGLOB(B0, B1, B2, B3, T, KK)                                         \
  { const unsigned long long* p_ = Bt + (size_t)((T) * 8 + (KK) * 4) * MDIM; \
    B0 = (long)p_[0];                                                        \
    B1 = (long)p_[16];                                                       \
    B2 = (long)p_[32];                                                       \
    B3 = (long)p_[48]; }

#define MFMA4(I, AF, B0, B1, B2, B3)                                                   \
  acc[I][0] = __builtin_amdgcn_mfma_f32_16x16x32_fp8_fp8(AF, B0, acc[I][0], 0, 0, 0);  \
  acc[I][1] = __builtin_amdgcn_mfma_f32_16x16x32_fp8_fp8(AF, B1, acc[I][1], 0, 0, 0);  \
  acc[I][2] = __builtin_amdgcn_mfma_f32_16x16x32_fp8_fp8(AF, B2, acc[I][2], 0, 0, 0);  \
  acc[I][3] = __builtin_amdgcn_mfma_f32_16x16x32_fp8_fp8(AF, B3, acc[I][3], 0, 0, 0);

#define MFMA32(S, B0, B1, B2, B3)                                            \
  __builtin_amdgcn_s_setprio(1);                                             \
  MFMA4(0, S##0, B0, B1, B2, B3) MFMA4(1, S##1, B0, B1, B2, B3)              \
  MFMA4(2, S##2, B0, B1, B2, B3) MFMA4(3, S##3, B0, B1, B2, B3)              \
  MFMA4(4, S##4, B0, B1, B2, B3) MFMA4(5, S##5, B0, B1, B2, B3)              \
  MFMA4(6, S##6, B0, B1, B2, B3) MFMA4(7, S##7, B0, B1, B2, B3)              \
  __builtin_amdgcn_s_setprio(0);

  // ---- prologue: SA(0,0) SA(0,1) SA(1,0) [3] + Bu(0,0) [4] ----
  STAGE(0, 0);
  STAGE(0, 1);
  STAGE(1, 0);
  BGLOB(u0, u1, u2, u3, 0, 0);
  SCHED0;
  VMCNT(5);                      // retire SA(0,0),SA(0,1); 5 in flight
  BAR;
  AREAD(s0_, 0, 0);

  // ---- main loop t = 0..13 uniform; peel t = 14, 15 ----
  for (int t = 0; t < 14; ++t) {
    // ph0: compute s0_ x U; read-ahead A(t,1); prefetch B(t,1)->V; SA(t+1,1)
    AREAD(s1_, t, 1);
    BGLOB(v0, v1, v2, v3, t, 1);
    SCHED0;
    LGKM(8); SCHED0;
    MFMA32(s0_, u0, u1, u2, u3);
    STAGE(t + 1, 1);
    VMCNT(5);                    // retire SA(t+1,0); leave {Bv4, SA(t+1,1)}
    BAR;
    // ph1: compute s1_ x V; read-ahead A(t+1,0); prefetch B(t+1,0)->U; SA(t+2,0)
    AREAD(s0_, t + 1, 0);
    BGLOB(u0, u1, u2, u3, t + 1, 0);
    SCHED0;
    LGKM(8); SCHED0;
    MFMA32(s1_, v0, v1, v2, v3);
    STAGE(t + 2, 0);
    VMCNT(5);                    // retire SA(t+1,1); leave {Bu4, SA(t+2,0)}
    BAR;
  }
  // t = 14
  AREAD(s1_, 14, 1);
  BGLOB(v0, v1, v2, v3, 14, 1);
  SCHED0;
  LGKM(8); SCHED0;
  MFMA32(s0_, u0, u1, u2, u3);
  STAGE(15, 1);
  VMCNT(5);                      // retire SA(15,0)
  BAR;
  AREAD(s0_, 15, 0);
  BGLOB(u0, u1, u2, u3, 15, 0);
  SCHED0;
  LGKM(8); SCHED0;
  MFMA32(s1_, v0, v1, v2, v3);
  VMCNT(4);                      // retire SA(15,1); leave Bu4
  BAR;
  // t = 15
  AREAD(s1_, 15, 1);
  BGLOB(v0, v1, v2, v3, 15, 1);
  SCHED0;
  LGKM(8); SCHED0;
  MFMA32(s0_, u0, u1, u2, u3);
  LGKM(0); SCHED0;
  MFMA32(s1_, v0, v1, v2, v3);

  // ---- epilogue: out = s*acc; C/D layout col=lane&15, row=(lane>>4)*4+j ----
  int crow = brow + wm * 128 + (lane >> 4) * 4;
  int ccol = bcol + wn * 64 + (lane & 15);
  #pragma unroll
  for (int mi = 0; mi < 8; ++mi)
    #pragma unroll
    for (int n = 0; n < 4; ++n)
      #pragma unroll
      for (int j = 0; j < 4; ++j)
        C[(size_t)(crow + mi * 16 + j) * MDIM + (ccol + n * 16)] = s_val * acc[mi][n][j];
}

extern "C" void kernel_launch(void* const* d_in, const int* in_sizes, int n_in,
                              void* d_out, int out_size, void* d_ws, size_t ws_size,
                              hipStream_t stream) {
  const float* x     = (const float*)d_in[0];
  const float* y     = (const float*)d_in[1];
  const float* freqs = (const float*)d_in[2];
  const float* lam   = (const float*)d_in[3];
  const float* var   = (const float*)d_in[4];
  float* out = (float*)d_out;
  float* ws  = (float*)d_ws;

  hipLaunchKernelGGL(scale_kernel, dim3(1), dim3(512), 0, stream, lam, var, ws);
  hipLaunchKernelGGL(phase_kernel, dim3(2048), dim3(256), 0, stream,
                     x, y, freqs, lam);
  hipLaunchKernelGGL(gemm_kernel, dim3((NDIM / 256) * (MDIM / 256)), dim3(512), 0, stream,
                     out, ws);
}